// Round 10
// baseline (460.354 us; speedup 1.0000x reference)
//
#include <hip/hip_runtime.h>
#include <math.h>

// n=16384 Gaussian points in 3D. Exact 12-NN (incl self) per point:
//   out[i] = b + ( (W·p_i)·(1 + 11/sqrt(2)) + 0.5 * sum_{11NN} W·|p_i - p_j| ) / 12
//
// R10: x-bin counting sort (self-zeroing, 1 dispatch) + persistent waves
// (atomic queue), one query per wave:
//   1. seed [t-384,t+384): per-lane MIN of d2 only (11 inst/step).
//   2. u = 12th smallest of the 64 lane minima (knockout) — valid UB of the
//      union 12th (the 12 smallest lane-minima are 12 distinct candidates <= u).
//   3. collect-scan seed + march out until (x-gap - binwidth)^2 > u:
//      d2 <= u -> 4-deep sorted paired (d2,w) buffer + count (8 VGPRs total;
//      R9's 24-VGPR list spilled to scratch = 3x WRITE_SIZE, 2.8x slower).
//   4. no lane overflowed (count<=4, ~always): 12-round paired knockout
//      (first-lane tie-break) extracts the exact 12 smallest, accumulating w.
//      Else (wave-uniform, rare): R8 fallback over the same extent — med3
//      12-deep -> exact tau -> masked rescan. Extent covers {d2<=u} superset
//      of {d2<=tau}, so both paths are exact. Self contributes w=0.

#define NBINS  2048
#define XMIN_  (-6.0f)
#define INVBW_ ((float)NBINS / 12.0f)
#define SLACK_ ((12.0f / (float)NBINS) * 1.02f)
#define SORTB  64
#define STHR   256
#define BLOCK  256
#define SEED   768
#define KK     12
#define CD     4            // collect depth per lane
#define BIG    3.0e38f

__device__ __forceinline__ int bin_of(float x) {
  int b = (int)((x - XMIN_) * INVBW_);
  b = b < 0 ? 0 : b;
  b = b > NBINS - 1 ? NBINS - 1 : b;
  return b;
}

__device__ __forceinline__ void gbar(int* c, int target) {
  __syncthreads();
  if (threadIdx.x == 0) {
    __threadfence();
    atomicAdd(c, 1);
    while (atomicAdd(c, 0) < target) __builtin_amdgcn_s_sleep(2);
    __threadfence();
  }
  __syncthreads();
}

__device__ __forceinline__ float wave_min(float v) {
#pragma unroll
  for (int o = 1; o < 64; o <<= 1) v = fminf(v, __shfl_xor(v, o));
  return v;
}

// sorted ascending 4-deep paired insert (static indexing -> registers)
__device__ __forceinline__ void ins4(float (&qd)[CD], float (&qw)[CD],
                                     float d, float w) {
#pragma unroll
  for (int k = CD - 1; k >= 1; --k) {
    const bool up  = (qd[k - 1] > d);
    const bool mid = (qd[k] > d);
    const float nd = up ? qd[k - 1] : (mid ? d : qd[k]);
    const float nw = up ? qw[k - 1] : (mid ? w : qw[k]);
    qd[k] = nd; qw[k] = nw;
  }
  if (qd[0] > d) { qw[0] = w; qd[0] = d; }
}

// ---------------- K1: fused counting sort (zero | hist | scan | scatter) -----
__global__ __launch_bounds__(STHR)
void sort_kernel(const float* __restrict__ p, int* __restrict__ hist,
                 int* __restrict__ cursor, int* __restrict__ cnt,
                 float4* __restrict__ sorted, int n) {
  __shared__ int ssum[STHR];
  const int tid = threadIdx.x;
  const int gid = blockIdx.x * STHR + tid;

  for (int i = gid; i < NBINS; i += SORTB * STHR) hist[i] = 0;
  gbar(&cnt[0], SORTB);

  for (int i = gid; i < n; i += SORTB * STHR)
    atomicAdd(&hist[bin_of(p[3 * i])], 1);
  gbar(&cnt[1], SORTB);

  if (blockIdx.x == 0) {
    const int base = tid * (NBINS / STHR);
    int v[NBINS / STHR];
    int sum = 0;
#pragma unroll
    for (int t = 0; t < NBINS / STHR; ++t) { v[t] = hist[base + t]; sum += v[t]; }
    ssum[tid] = sum;
    __syncthreads();
    for (int off = 1; off < STHR; off <<= 1) {
      const int x = (tid >= off) ? ssum[tid - off] : 0;
      __syncthreads();
      ssum[tid] += x;
      __syncthreads();
    }
    int run = (tid > 0) ? ssum[tid - 1] : 0;
#pragma unroll
    for (int t = 0; t < NBINS / STHR; ++t) { cursor[base + t] = run; run += v[t]; }
  }
  gbar(&cnt[2], SORTB);

  for (int i = gid; i < n; i += SORTB * STHR) {
    const float x = p[3 * i], y = p[3 * i + 1], z = p[3 * i + 2];
    const int pos = atomicAdd(&cursor[bin_of(x)], 1);
    sorted[pos] = make_float4(x, y, z, __int_as_float(i));
  }
}

// ---------------- K2: query (persistent waves, one query per grab) -----------
__global__ __launch_bounds__(BLOCK)
void query_kernel(const float4* __restrict__ sv, const float* __restrict__ W,
                  const float* __restrict__ bias, float* __restrict__ out,
                  int* __restrict__ qctr, int n) {
  const int lane = threadIdx.x & 63;
  const float W0 = W[0], W1 = W[1], W2 = W[2];
  const float bb = bias[0];

  for (;;) {
    int t;
    if (lane == 0) t = atomicAdd(qctr, 1);
    t = __shfl(t, 0);
    if (t >= n) break;

    const float4 me = sv[t];
    const float xi = me.x, yi = me.y, zi = me.z;
    const int orig = __float_as_int(me.w);

    int lo = t - SEED / 2;
    lo = lo < 0 ? 0 : lo;
    lo = lo > n - SEED ? n - SEED : lo;
    const float4* base = sv + lo + lane;

    // ---- 1. seed lane-minima (all positions valid by clamping) ----
    float m = BIG;
#pragma unroll
    for (int s = 0; s < SEED / 64; ++s) {
      const float4 c = base[s * 64];
      const float dx = xi - c.x, dy = yi - c.y, dz = zi - c.z;
      m = fminf(m, fmaf(dx, dx, fmaf(dy, dy, dz * dz)));
    }

    // ---- 2. u = 12th smallest of the 64 lane minima ----
    float u;
    {
      float v = m;
#pragma unroll
      for (int r = 0; r < KK; ++r) {
        const float mm = wave_min(v);
        u = mm;
        v = (v == mm) ? BIG : v;
      }
    }

    // ---- 3. collect-scan: seed + march, 4-deep paired buffer ----
    float qd[CD], qw[CD];
    int ccnt = 0;
#pragma unroll
    for (int k = 0; k < CD; ++k) { qd[k] = BIG; qw[k] = 0.f; }

#pragma unroll
    for (int s = 0; s < SEED / 64; ++s) {
      const float4 c = base[s * 64];
      const float dx = xi - c.x, dy = yi - c.y, dz = zi - c.z;
      const float d2 = fmaf(dx, dx, fmaf(dy, dy, dz * dz));
      if (d2 <= u) {
        const float w = fmaf(W0, fabsf(dx), fmaf(W1, fabsf(dy), W2 * fabsf(dz)));
        ++ccnt;
        ins4(qd, qw, d2, w);
      }
    }

    int rp = lo + SEED;
    while (rp < n) {
      const int pos = rp + lane;
      const bool vld = pos < n;
      const float4 c = sv[vld ? pos : n - 1];
      const float dx = xi - c.x, dy = yi - c.y, dz = zi - c.z;
      const float d2 = vld ? fmaf(dx, dx, fmaf(dy, dy, dz * dz)) : BIG;
      if (d2 <= u) {
        const float w = fmaf(W0, fabsf(dx), fmaf(W1, fabsf(dy), W2 * fabsf(dz)));
        ++ccnt;
        ins4(qd, qw, d2, w);
      }
      const float xf = __shfl(c.x, 63);
      rp += 64;
      const float gap = xf - SLACK_ - xi;
      if (gap > 0.f && gap * gap > u) break;
    }

    int lp = lo - 1;
    while (lp >= 0) {
      const int pos = lp - lane;
      const bool vld = pos >= 0;
      const float4 c = sv[vld ? pos : 0];
      const float dx = xi - c.x, dy = yi - c.y, dz = zi - c.z;
      const float d2 = vld ? fmaf(dx, dx, fmaf(dy, dy, dz * dz)) : BIG;
      if (d2 <= u) {
        const float w = fmaf(W0, fabsf(dx), fmaf(W1, fabsf(dy), W2 * fabsf(dz)));
        ++ccnt;
        ins4(qd, qw, d2, w);
      }
      const float xf = __shfl(c.x, 63);
      lp -= 64;
      const float gap = xi - SLACK_ - xf;
      if (gap > 0.f && gap * gap > u) break;
    }

    // ---- 4. extract exact 12 smallest ----
    float acc = 0.f;
    const bool ovf = __ballot(ccnt > CD) != 0ULL;   // wave-uniform
    if (!ovf) {
      // common path: 12-round paired knockout, first-lane tie-break
#pragma unroll
      for (int r = 0; r < KK; ++r) {
        const float mm = wave_min(qd[0]);
        const unsigned long long bal = __ballot(qd[0] == mm);
        if (qd[0] == mm && lane == (int)(__ffsll(bal) - 1)) {
          acc += qw[0];
#pragma unroll
          for (int k = 0; k < CD - 1; ++k) { qd[k] = qd[k + 1]; qw[k] = qw[k + 1]; }
          qd[CD - 1] = BIG;
        }
      }
    } else {
      // rare exact fallback over the same extent: med3 top-12 -> tau -> rescan
      int Lo = lp + 1; Lo = Lo < 0 ? 0 : Lo;
      int Hi = rp;     Hi = Hi > n ? n : Hi;
      float dd[KK];
#pragma unroll
      for (int k = 0; k < KK; ++k) dd[k] = BIG;
      for (int pos = Lo + lane; pos < Hi; pos += 64) {
        const float4 c = sv[pos];
        const float dx = xi - c.x, dy = yi - c.y, dz = zi - c.z;
        const float d2 = fmaf(dx, dx, fmaf(dy, dy, dz * dz));
#pragma unroll
        for (int k = KK - 1; k >= 1; --k)
          dd[k] = __builtin_amdgcn_fmed3f(d2, dd[k - 1], dd[k]);
        dd[0] = fminf(dd[0], d2);
      }
      float tau = 0.f;
#pragma unroll
      for (int r = 0; r < KK; ++r) {
        const float mm = wave_min(dd[0]);
        if (dd[0] == mm) {
#pragma unroll
          for (int k = 0; k < KK - 1; ++k) dd[k] = dd[k + 1];
          dd[KK - 1] = BIG;
        }
        tau = mm;
      }
      for (int pos = Lo + lane; pos < Hi; pos += 64) {
        const float4 c = sv[pos];
        const float dx = xi - c.x, dy = yi - c.y, dz = zi - c.z;
        const float d2 = fmaf(dx, dx, fmaf(dy, dy, dz * dz));
        const float w  = fmaf(W0, fabsf(dx), fmaf(W1, fabsf(dy), W2 * fabsf(dz)));
        acc += (d2 <= tau) ? w : 0.f;
      }
    }

    // ---- 5. reduce + write ----
#pragma unroll
    for (int o = 1; o < 64; o <<= 1) acc += __shfl_xor(acc, o);
    if (lane == 0) {
      const float xw0 = W0 * xi + W1 * yi + W2 * zi;
      // 1 + 11/sqrt(2)
      out[orig] = bb + (xw0 * 8.778174593052022f + 0.5f * acc) * (1.0f / 12.0f);
    }
  }
}

extern "C" void kernel_launch(void* const* d_in, const int* in_sizes, int n_in,
                              void* d_out, int out_size, void* d_ws, size_t ws_size,
                              hipStream_t stream) {
  const float* p  = (const float*)d_in[0];
  const float* W  = (const float*)d_in[1];
  const float* bb = (const float*)d_in[2];
  float* out = (float*)d_out;

  const int n = in_sizes[0] / 3;   // 16384

  // ws: hist[2048] @0 | cnt[3] @8192 | qctr @8240 | cursor[2048] @8256 | sorted @16448
  int*    hist   = (int*)d_ws;
  int*    cnt    = (int*)((char*)d_ws + 8192);
  int*    qctr   = (int*)((char*)d_ws + 8240);
  int*    cursor = (int*)((char*)d_ws + 8256);
  float4* sorted = (float4*)((char*)d_ws + 16448);

  hipMemsetAsync((char*)d_ws + 8192, 0, 64, stream);   // cnt + qctr only
  sort_kernel<<<SORTB, STHR, 0, stream>>>(p, hist, cursor, cnt, sorted, n);
  query_kernel<<<2048, BLOCK, 0, stream>>>(sorted, W, bb, out, qctr, n);
}

// Round 11
// 265.375 us; speedup vs baseline: 1.7347x; 1.7347x over previous
//
#include <hip/hip_runtime.h>
#include <math.h>

// n=16384 Gaussian points in 3D. Exact 12-NN (incl self) per point:
//   out[i] = b + ( (W·p_i)·(1 + 11/sqrt(2)) + 0.5 * sum_{11NN} W·|p_i - p_j| ) / 12
//
// R11: x-bin counting sort (self-zeroing, 1 dispatch), then ONE WAVE PER QUERY
// with STATIC INTERLEAVED assignment (no atomic queue — R9/R10's single-counter
// queue serialized 16384 cross-XCD atomics ≈ 400 µs and bounced its cache line
// to HBM: WRITE_SIZE 334->1104 KB). Block b, wave v -> query t = v*(n/4) + b:
// each block spans all 4 sorted-position quartiles -> per-block cost ~ 4*mean.
// Per query:
//   1. seed [t-384,t+384): per-lane MIN of d2 (11 inst/step).
//   2. u = 12th smallest of the 64 lane minima (knockout) — valid UB of the
//      union 12th (12 smallest lane-minima are 12 distinct candidates <= u).
//   3. collect-scan seed + march until (x-gap - binwidth)^2 > u:
//      d2 <= u (exec-masked, ~1/3 of steps) -> 4-deep sorted paired (d2,w)
//      buffer + count (8 VGPRs; no spill at VGPR=40).
//   4. count<=4 everywhere (~always): 12-round paired knockout (first-lane
//      tie-break) extracts exact 12 smallest, accumulating w. Else wave-uniform
//      exact fallback over the same extent (med3 top-12 -> tau -> masked
//      rescan); extent covers {d2<=u} ⊇ {d2<=tau}. Self contributes w=0.

#define NBINS  2048
#define XMIN_  (-6.0f)
#define INVBW_ ((float)NBINS / 12.0f)
#define SLACK_ ((12.0f / (float)NBINS) * 1.02f)
#define SORTB  64
#define STHR   256
#define BLOCK  256
#define WPB    4
#define SEED   768
#define KK     12
#define CD     4            // collect depth per lane
#define BIG    3.0e38f

__device__ __forceinline__ int bin_of(float x) {
  int b = (int)((x - XMIN_) * INVBW_);
  b = b < 0 ? 0 : b;
  b = b > NBINS - 1 ? NBINS - 1 : b;
  return b;
}

__device__ __forceinline__ void gbar(int* c, int target) {
  __syncthreads();
  if (threadIdx.x == 0) {
    __threadfence();
    atomicAdd(c, 1);
    while (atomicAdd(c, 0) < target) __builtin_amdgcn_s_sleep(2);
    __threadfence();
  }
  __syncthreads();
}

__device__ __forceinline__ float wave_min(float v) {
#pragma unroll
  for (int o = 1; o < 64; o <<= 1) v = fminf(v, __shfl_xor(v, o));
  return v;
}

// sorted ascending 4-deep paired insert (static indexing -> registers)
__device__ __forceinline__ void ins4(float (&qd)[CD], float (&qw)[CD],
                                     float d, float w) {
#pragma unroll
  for (int k = CD - 1; k >= 1; --k) {
    const bool up  = (qd[k - 1] > d);
    const bool mid = (qd[k] > d);
    const float nd = up ? qd[k - 1] : (mid ? d : qd[k]);
    const float nw = up ? qw[k - 1] : (mid ? w : qw[k]);
    qd[k] = nd; qw[k] = nw;
  }
  if (qd[0] > d) { qw[0] = w; qd[0] = d; }
}

// ---------------- K1: fused counting sort (zero | hist | scan | scatter) -----
__global__ __launch_bounds__(STHR)
void sort_kernel(const float* __restrict__ p, int* __restrict__ hist,
                 int* __restrict__ cursor, int* __restrict__ cnt,
                 float4* __restrict__ sorted, int n) {
  __shared__ int ssum[STHR];
  const int tid = threadIdx.x;
  const int gid = blockIdx.x * STHR + tid;

  for (int i = gid; i < NBINS; i += SORTB * STHR) hist[i] = 0;
  gbar(&cnt[0], SORTB);

  for (int i = gid; i < n; i += SORTB * STHR)
    atomicAdd(&hist[bin_of(p[3 * i])], 1);
  gbar(&cnt[1], SORTB);

  if (blockIdx.x == 0) {
    const int base = tid * (NBINS / STHR);
    int v[NBINS / STHR];
    int sum = 0;
#pragma unroll
    for (int t = 0; t < NBINS / STHR; ++t) { v[t] = hist[base + t]; sum += v[t]; }
    ssum[tid] = sum;
    __syncthreads();
    for (int off = 1; off < STHR; off <<= 1) {
      const int x = (tid >= off) ? ssum[tid - off] : 0;
      __syncthreads();
      ssum[tid] += x;
      __syncthreads();
    }
    int run = (tid > 0) ? ssum[tid - 1] : 0;
#pragma unroll
    for (int t = 0; t < NBINS / STHR; ++t) { cursor[base + t] = run; run += v[t]; }
  }
  gbar(&cnt[2], SORTB);

  for (int i = gid; i < n; i += SORTB * STHR) {
    const float x = p[3 * i], y = p[3 * i + 1], z = p[3 * i + 2];
    const int pos = atomicAdd(&cursor[bin_of(x)], 1);
    sorted[pos] = make_float4(x, y, z, __int_as_float(i));
  }
}

// ---------------- K2: query (one wave per query, static interleave) ----------
__global__ __launch_bounds__(BLOCK)
void query_kernel(const float4* __restrict__ sv, const float* __restrict__ W,
                  const float* __restrict__ bias, float* __restrict__ out, int n) {
  const int lane = threadIdx.x & 63;
  const int wv   = threadIdx.x >> 6;                 // wave in block, 0..3
  const int t    = wv * (n >> 2) + blockIdx.x;       // quartile interleave
  const float W0 = W[0], W1 = W[1], W2 = W[2];
  const float bb = bias[0];

  const float4 me = sv[t];
  const float xi = me.x, yi = me.y, zi = me.z;
  const int orig = __float_as_int(me.w);

  int lo = t - SEED / 2;
  lo = lo < 0 ? 0 : lo;
  lo = lo > n - SEED ? n - SEED : lo;
  const float4* base = sv + lo + lane;

  // ---- 1. seed lane-minima ----
  float m = BIG;
#pragma unroll
  for (int s = 0; s < SEED / 64; ++s) {
    const float4 c = base[s * 64];
    const float dx = xi - c.x, dy = yi - c.y, dz = zi - c.z;
    m = fminf(m, fmaf(dx, dx, fmaf(dy, dy, dz * dz)));
  }

  // ---- 2. u = 12th smallest of the 64 lane minima ----
  float u;
  {
    float v = m;
#pragma unroll
    for (int r = 0; r < KK; ++r) {
      const float mm = wave_min(v);
      u = mm;
      v = (v == mm) ? BIG : v;
    }
  }

  // ---- 3. collect-scan: seed + march, 4-deep paired buffer ----
  float qd[CD], qw[CD];
  int ccnt = 0;
#pragma unroll
  for (int k = 0; k < CD; ++k) { qd[k] = BIG; qw[k] = 0.f; }

#pragma unroll
  for (int s = 0; s < SEED / 64; ++s) {
    const float4 c = base[s * 64];
    const float dx = xi - c.x, dy = yi - c.y, dz = zi - c.z;
    const float d2 = fmaf(dx, dx, fmaf(dy, dy, dz * dz));
    if (d2 <= u) {
      const float w = fmaf(W0, fabsf(dx), fmaf(W1, fabsf(dy), W2 * fabsf(dz)));
      ++ccnt;
      ins4(qd, qw, d2, w);
    }
  }

  int rp = lo + SEED;
  while (rp < n) {
    const int pos = rp + lane;
    const bool vld = pos < n;
    const float4 c = sv[vld ? pos : n - 1];
    const float dx = xi - c.x, dy = yi - c.y, dz = zi - c.z;
    const float d2 = vld ? fmaf(dx, dx, fmaf(dy, dy, dz * dz)) : BIG;
    if (d2 <= u) {
      const float w = fmaf(W0, fabsf(dx), fmaf(W1, fabsf(dy), W2 * fabsf(dz)));
      ++ccnt;
      ins4(qd, qw, d2, w);
    }
    const float xf = __shfl(c.x, 63);
    rp += 64;
    const float gap = xf - SLACK_ - xi;
    if (gap > 0.f && gap * gap > u) break;
  }

  int lp = lo - 1;
  while (lp >= 0) {
    const int pos = lp - lane;
    const bool vld = pos >= 0;
    const float4 c = sv[vld ? pos : 0];
    const float dx = xi - c.x, dy = yi - c.y, dz = zi - c.z;
    const float d2 = vld ? fmaf(dx, dx, fmaf(dy, dy, dz * dz)) : BIG;
    if (d2 <= u) {
      const float w = fmaf(W0, fabsf(dx), fmaf(W1, fabsf(dy), W2 * fabsf(dz)));
      ++ccnt;
      ins4(qd, qw, d2, w);
    }
    const float xf = __shfl(c.x, 63);
    lp -= 64;
    const float gap = xi - SLACK_ - xf;
    if (gap > 0.f && gap * gap > u) break;
  }

  // ---- 4. extract exact 12 smallest ----
  float acc = 0.f;
  const bool ovf = __ballot(ccnt > CD) != 0ULL;   // wave-uniform
  if (!ovf) {
#pragma unroll
    for (int r = 0; r < KK; ++r) {
      const float mm = wave_min(qd[0]);
      const unsigned long long bal = __ballot(qd[0] == mm);
      if (qd[0] == mm && lane == (int)(__ffsll(bal) - 1)) {
        acc += qw[0];
#pragma unroll
        for (int k = 0; k < CD - 1; ++k) { qd[k] = qd[k + 1]; qw[k] = qw[k + 1]; }
        qd[CD - 1] = BIG;
      }
    }
  } else {
    // rare exact fallback over the same extent: med3 top-12 -> tau -> rescan
    int Lo = lp + 1; Lo = Lo < 0 ? 0 : Lo;
    int Hi = rp;     Hi = Hi > n ? n : Hi;
    float dd[KK];
#pragma unroll
    for (int k = 0; k < KK; ++k) dd[k] = BIG;
    for (int pos = Lo + lane; pos < Hi; pos += 64) {
      const float4 c = sv[pos];
      const float dx = xi - c.x, dy = yi - c.y, dz = zi - c.z;
      const float d2 = fmaf(dx, dx, fmaf(dy, dy, dz * dz));
#pragma unroll
      for (int k = KK - 1; k >= 1; --k)
        dd[k] = __builtin_amdgcn_fmed3f(d2, dd[k - 1], dd[k]);
      dd[0] = fminf(dd[0], d2);
    }
    float tau = 0.f;
#pragma unroll
    for (int r = 0; r < KK; ++r) {
      const float mm = wave_min(dd[0]);
      if (dd[0] == mm) {
#pragma unroll
        for (int k = 0; k < KK - 1; ++k) dd[k] = dd[k + 1];
        dd[KK - 1] = BIG;
      }
      tau = mm;
    }
    for (int pos = Lo + lane; pos < Hi; pos += 64) {
      const float4 c = sv[pos];
      const float dx = xi - c.x, dy = yi - c.y, dz = zi - c.z;
      const float d2 = fmaf(dx, dx, fmaf(dy, dy, dz * dz));
      const float w  = fmaf(W0, fabsf(dx), fmaf(W1, fabsf(dy), W2 * fabsf(dz)));
      acc += (d2 <= tau) ? w : 0.f;
    }
  }

  // ---- 5. reduce + write ----
#pragma unroll
  for (int o = 1; o < 64; o <<= 1) acc += __shfl_xor(acc, o);
  if (lane == 0) {
    const float xw0 = W0 * xi + W1 * yi + W2 * zi;
    // 1 + 11/sqrt(2)
    out[orig] = bb + (xw0 * 8.778174593052022f + 0.5f * acc) * (1.0f / 12.0f);
  }
}

extern "C" void kernel_launch(void* const* d_in, const int* in_sizes, int n_in,
                              void* d_out, int out_size, void* d_ws, size_t ws_size,
                              hipStream_t stream) {
  const float* p  = (const float*)d_in[0];
  const float* W  = (const float*)d_in[1];
  const float* bb = (const float*)d_in[2];
  float* out = (float*)d_out;

  const int n = in_sizes[0] / 3;   // 16384

  // ws: hist[2048] @0 | cnt[3] @8192 | cursor[2048] @8256 | sorted @16448
  int*    hist   = (int*)d_ws;
  int*    cnt    = (int*)((char*)d_ws + 8192);
  int*    cursor = (int*)((char*)d_ws + 8256);
  float4* sorted = (float4*)((char*)d_ws + 16448);

  hipMemsetAsync((char*)d_ws + 8192, 0, 64, stream);   // cnt
  sort_kernel<<<SORTB, STHR, 0, stream>>>(p, hist, cursor, cnt, sorted, n);
  query_kernel<<<n / WPB, BLOCK, 0, stream>>>(sorted, W, bb, out, n);
}

// Round 12
// 246.095 us; speedup vs baseline: 1.8706x; 1.0783x over previous
//
#include <hip/hip_runtime.h>
#include <math.h>

// n=16384 Gaussian points in 3D. Exact 12-NN (incl self) per point:
//   out[i] = b + ( (W·p_i)·(1 + 11/sqrt(2)) + 0.5 * sum_{11NN} W·|p_i - p_j| ) / 12
//
// R12: x-bin counting sort (self-zeroing, 1 dispatch) + one wave per query,
// static quartile interleave (t = wv*(n/4) + blockIdx.x). Per query:
//   1. seed [t-384,t+384): per-lane MIN of d2 (pipelined, no deps).
//   2. u = 12th smallest of the 64 lane minima (knockout). Valid UB of true
//      tau: >=12 distinct candidates (distinct lanes) have d2 <= u.
//   3. EXTENT FROM PREFIX SUMS (kills R11's serial load->shfl->break march):
//      every point with d2<=u has |x-xi|<=sqrt(u); cursor[] gives the sorted-
//      position range of bins [bin(xi-s), bin(xi+s)] in O(1). Fixed-trip,
//      break-free, shuffle-free collect loop (~12 inst/step, unrolled x2):
//      d2<=u -> 4-deep sorted paired (d2,w) buffer + count.
//   4. no overflow (~always): 12-round paired knockout (first-lane tie-break)
//      extracts exact 12 smallest, accumulating w. Overflow (outlier queries,
//      wave-uniform): med3 12-deep over the same extent -> tau -> masked
//      rescan; all passes fixed-trip and pipelined, so even degenerate
//      queries cost ~3 issue-bound passes, not 100 us of chained latency.
//   5. wave-reduce, lane 0 writes. Self contributes w=0.

#define NBINS  2048
#define XMIN_  (-6.0f)
#define INVBW_ ((float)NBINS / 12.0f)
#define SORTB  64
#define STHR   256
#define BLOCK  256
#define WPB    4
#define SEED   768
#define KK     12
#define CD     4            // collect depth per lane
#define BIG    3.0e38f

__device__ __forceinline__ int bin_of(float x) {
  int b = (int)((x - XMIN_) * INVBW_);
  b = b < 0 ? 0 : b;
  b = b > NBINS - 1 ? NBINS - 1 : b;
  return b;
}

__device__ __forceinline__ void gbar(int* c, int target) {
  __syncthreads();
  if (threadIdx.x == 0) {
    __threadfence();
    atomicAdd(c, 1);
    while (atomicAdd(c, 0) < target) __builtin_amdgcn_s_sleep(2);
    __threadfence();
  }
  __syncthreads();
}

__device__ __forceinline__ float wave_min(float v) {
#pragma unroll
  for (int o = 1; o < 64; o <<= 1) v = fminf(v, __shfl_xor(v, o));
  return v;
}

// sorted ascending 4-deep paired insert (static indexing -> registers)
__device__ __forceinline__ void ins4(float (&qd)[CD], float (&qw)[CD],
                                     float d, float w) {
#pragma unroll
  for (int k = CD - 1; k >= 1; --k) {
    const bool up  = (qd[k - 1] > d);
    const bool mid = (qd[k] > d);
    const float nd = up ? qd[k - 1] : (mid ? d : qd[k]);
    const float nw = up ? qw[k - 1] : (mid ? w : qw[k]);
    qd[k] = nd; qw[k] = nw;
  }
  if (qd[0] > d) { qw[0] = w; qd[0] = d; }
}

// ---------------- K1: fused counting sort (zero | hist | scan | scatter) -----
__global__ __launch_bounds__(STHR)
void sort_kernel(const float* __restrict__ p, int* __restrict__ hist,
                 int* __restrict__ cursor, int* __restrict__ cnt,
                 float4* __restrict__ sorted, int n) {
  __shared__ int ssum[STHR];
  const int tid = threadIdx.x;
  const int gid = blockIdx.x * STHR + tid;

  for (int i = gid; i < NBINS; i += SORTB * STHR) hist[i] = 0;
  gbar(&cnt[0], SORTB);

  for (int i = gid; i < n; i += SORTB * STHR)
    atomicAdd(&hist[bin_of(p[3 * i])], 1);
  gbar(&cnt[1], SORTB);

  if (blockIdx.x == 0) {
    const int base = tid * (NBINS / STHR);
    int v[NBINS / STHR];
    int sum = 0;
#pragma unroll
    for (int t = 0; t < NBINS / STHR; ++t) { v[t] = hist[base + t]; sum += v[t]; }
    ssum[tid] = sum;
    __syncthreads();
    for (int off = 1; off < STHR; off <<= 1) {
      const int x = (tid >= off) ? ssum[tid - off] : 0;
      __syncthreads();
      ssum[tid] += x;
      __syncthreads();
    }
    int run = (tid > 0) ? ssum[tid - 1] : 0;
#pragma unroll
    for (int t = 0; t < NBINS / STHR; ++t) { cursor[base + t] = run; run += v[t]; }
  }
  gbar(&cnt[2], SORTB);

  for (int i = gid; i < n; i += SORTB * STHR) {
    const float x = p[3 * i], y = p[3 * i + 1], z = p[3 * i + 2];
    const int pos = atomicAdd(&cursor[bin_of(x)], 1);
    sorted[pos] = make_float4(x, y, z, __int_as_float(i));
  }
  // post: cursor[b] = end of bin b (= start of bin b+1)
}

// ---------------- K2: query (one wave per query, precomputed extent) ---------
__global__ __launch_bounds__(BLOCK)
void query_kernel(const float4* __restrict__ sv, const int* __restrict__ cursor,
                  const float* __restrict__ W, const float* __restrict__ bias,
                  float* __restrict__ out, int n) {
  const int lane = threadIdx.x & 63;
  const int wv   = threadIdx.x >> 6;                 // wave in block, 0..3
  const int t    = wv * (n >> 2) + blockIdx.x;       // quartile interleave
  const float W0 = W[0], W1 = W[1], W2 = W[2];
  const float bb = bias[0];

  const float4 me = sv[t];
  const float xi = me.x, yi = me.y, zi = me.z;
  const int orig = __float_as_int(me.w);

  int lo = t - SEED / 2;
  lo = lo < 0 ? 0 : lo;
  lo = lo > n - SEED ? n - SEED : lo;
  const float4* base = sv + lo + lane;

  // ---- 1. seed lane-minima (independent loads, pipeline freely) ----
  float m = BIG;
#pragma unroll
  for (int s = 0; s < SEED / 64; ++s) {
    const float4 c = base[s * 64];
    const float dx = xi - c.x, dy = yi - c.y, dz = zi - c.z;
    m = fminf(m, fmaf(dx, dx, fmaf(dy, dy, dz * dz)));
  }

  // ---- 2. u = 12th smallest of the 64 lane minima ----
  float u;
  {
    float v = m;
#pragma unroll
    for (int r = 0; r < KK; ++r) {
      const float mm = wave_min(v);
      u = mm;
      v = (v == mm) ? BIG : v;
    }
  }

  // ---- 3. extent from prefix sums: {|x-xi| <= sqrt(u)} ⊆ [lo2, hi2) ----
  const float s = sqrtf(u);
  const int bl = bin_of(xi - s);
  const int bh = bin_of(xi + s);
  const int lo2 = (bl > 0) ? cursor[bl - 1] : 0;
  const int hi2 = cursor[bh];
  const int steps = (hi2 - lo2 + 63) >> 6;

  // ---- collect-scan: fixed-trip, break-free, unrolled x2 ----
  float qd[CD], qw[CD];
  int ccnt = 0;
#pragma unroll
  for (int k = 0; k < CD; ++k) { qd[k] = BIG; qw[k] = 0.f; }

  int st = 0;
  for (; st + 2 <= steps; st += 2) {
    const int p0 = lo2 + st * 64 + lane;
    const int p1 = p0 + 64;
    const float4 c0 = sv[p0];
    const float4 c1 = sv[(p1 < hi2) ? p1 : hi2 - 1];
    {
      const float dx = xi - c0.x, dy = yi - c0.y, dz = zi - c0.z;
      const float d2 = fmaf(dx, dx, fmaf(dy, dy, dz * dz));
      if (d2 <= u) {
        const float w = fmaf(W0, fabsf(dx), fmaf(W1, fabsf(dy), W2 * fabsf(dz)));
        ++ccnt; ins4(qd, qw, d2, w);
      }
    }
    if (p1 < hi2) {
      const float dx = xi - c1.x, dy = yi - c1.y, dz = zi - c1.z;
      const float d2 = fmaf(dx, dx, fmaf(dy, dy, dz * dz));
      if (d2 <= u) {
        const float w = fmaf(W0, fabsf(dx), fmaf(W1, fabsf(dy), W2 * fabsf(dz)));
        ++ccnt; ins4(qd, qw, d2, w);
      }
    }
  }
  for (; st < steps; ++st) {
    const int pos = lo2 + st * 64 + lane;
    if (pos < hi2) {
      const float4 c = sv[pos];
      const float dx = xi - c.x, dy = yi - c.y, dz = zi - c.z;
      const float d2 = fmaf(dx, dx, fmaf(dy, dy, dz * dz));
      if (d2 <= u) {
        const float w = fmaf(W0, fabsf(dx), fmaf(W1, fabsf(dy), W2 * fabsf(dz)));
        ++ccnt; ins4(qd, qw, d2, w);
      }
    }
  }

  // ---- 4. extract exact 12 smallest ----
  float acc = 0.f;
  const bool ovf = __ballot(ccnt > CD) != 0ULL;   // wave-uniform
  if (!ovf) {
#pragma unroll
    for (int r = 0; r < KK; ++r) {
      const float mm = wave_min(qd[0]);
      const unsigned long long bal = __ballot(qd[0] == mm);
      if (qd[0] == mm && lane == (int)(__ffsll(bal) - 1)) {
        acc += qw[0];
#pragma unroll
        for (int k = 0; k < CD - 1; ++k) { qd[k] = qd[k + 1]; qw[k] = qw[k + 1]; }
        qd[CD - 1] = BIG;
      }
    }
  } else {
    // rare exact fallback over the same extent: med3 top-12 -> tau -> rescan
    float dd[KK];
#pragma unroll
    for (int k = 0; k < KK; ++k) dd[k] = BIG;
    for (int s0 = 0; s0 < steps; ++s0) {
      const int pos = lo2 + s0 * 64 + lane;
      const float4 c = sv[(pos < hi2) ? pos : hi2 - 1];
      const float dx = xi - c.x, dy = yi - c.y, dz = zi - c.z;
      const float d2 = (pos < hi2) ? fmaf(dx, dx, fmaf(dy, dy, dz * dz)) : BIG;
#pragma unroll
      for (int k = KK - 1; k >= 1; --k)
        dd[k] = __builtin_amdgcn_fmed3f(d2, dd[k - 1], dd[k]);
      dd[0] = fminf(dd[0], d2);
    }
    float tau = 0.f;
#pragma unroll
    for (int r = 0; r < KK; ++r) {
      const float mm = wave_min(dd[0]);
      if (dd[0] == mm) {
#pragma unroll
        for (int k = 0; k < KK - 1; ++k) dd[k] = dd[k + 1];
        dd[KK - 1] = BIG;
      }
      tau = mm;
    }
    for (int s0 = 0; s0 < steps; ++s0) {
      const int pos = lo2 + s0 * 64 + lane;
      if (pos < hi2) {
        const float4 c = sv[pos];
        const float dx = xi - c.x, dy = yi - c.y, dz = zi - c.z;
        const float d2 = fmaf(dx, dx, fmaf(dy, dy, dz * dz));
        const float w  = fmaf(W0, fabsf(dx), fmaf(W1, fabsf(dy), W2 * fabsf(dz)));
        acc += (d2 <= tau) ? w : 0.f;
      }
    }
  }

  // ---- 5. reduce + write ----
#pragma unroll
  for (int o = 1; o < 64; o <<= 1) acc += __shfl_xor(acc, o);
  if (lane == 0) {
    const float xw0 = W0 * xi + W1 * yi + W2 * zi;
    // 1 + 11/sqrt(2)
    out[orig] = bb + (xw0 * 8.778174593052022f + 0.5f * acc) * (1.0f / 12.0f);
  }
}

extern "C" void kernel_launch(void* const* d_in, const int* in_sizes, int n_in,
                              void* d_out, int out_size, void* d_ws, size_t ws_size,
                              hipStream_t stream) {
  const float* p  = (const float*)d_in[0];
  const float* W  = (const float*)d_in[1];
  const float* bb = (const float*)d_in[2];
  float* out = (float*)d_out;

  const int n = in_sizes[0] / 3;   // 16384

  // ws: hist[2048] @0 | cnt[3] @8192 | cursor[2048] @8256 | sorted @16448
  int*    hist   = (int*)d_ws;
  int*    cnt    = (int*)((char*)d_ws + 8192);
  int*    cursor = (int*)((char*)d_ws + 8256);
  float4* sorted = (float4*)((char*)d_ws + 16448);

  hipMemsetAsync((char*)d_ws + 8192, 0, 64, stream);   // cnt
  sort_kernel<<<SORTB, STHR, 0, stream>>>(p, hist, cursor, cnt, sorted, n);
  query_kernel<<<n / WPB, BLOCK, 0, stream>>>(sorted, cursor, W, bb, out, n);
}

// Round 13
// 166.592 us; speedup vs baseline: 2.7634x; 1.4772x over previous
//
#include <hip/hip_runtime.h>
#include <math.h>

// n=16384 Gaussian points in 3D. Exact 12-NN (incl self) per point:
//   out[i] = b + ( (W·p_i)·(1 + 11/sqrt(2)) + 0.5 * sum_{11NN} W·|p_i - p_j| ) / 12
//
// R13: THREE counting sorts (one per axis; 3 independent single-block kernels,
// LDS hist+scan, no global barriers, no memset). Query: one wave per query;
// each query picks the axis with max |coord| (wave-uniform) — slab mass
// Φ(c+s)-Φ(c-s) is minimized by the largest projection, so extents are ~30
// steps for ALL queries (central and outlier alike; outliers were R12's 4450
// avg inst/wave). Then R12's proven path on the chosen axis:
//   seed 768 around bin-estimated rank -> per-lane min d2 -> u = 12th of 64
//   lane minima (valid UB of tau) -> extent from prefix sums -> fixed-trip
//   collect into 4-deep paired (d2,w) buffer -> 12-round paired knockout
//   (exact take-12, first-lane tie-break) -> reduce, write. Overflow (rare,
//   wave-uniform) -> exact med3 fallback over the same extent.

#define NBINS  2048
#define CMIN_  (-6.0f)
#define INVBW_ ((float)NBINS / 12.0f)
#define BLOCK  256
#define WPB    4
#define SEED   768
#define KK     12
#define CD     4
#define BIG    3.0e38f

__device__ __forceinline__ int bin_of(float x) {
  int b = (int)((x - CMIN_) * INVBW_);
  b = b < 0 ? 0 : b;
  b = b > NBINS - 1 ? NBINS - 1 : b;
  return b;
}

__device__ __forceinline__ float wave_min(float v) {
#pragma unroll
  for (int o = 1; o < 64; o <<= 1) v = fminf(v, __shfl_xor(v, o));
  return v;
}

// sorted ascending 4-deep paired insert (static indexing -> registers)
__device__ __forceinline__ void ins4(float (&qd)[CD], float (&qw)[CD],
                                     float d, float w) {
#pragma unroll
  for (int k = CD - 1; k >= 1; --k) {
    const bool up  = (qd[k - 1] > d);
    const bool mid = (qd[k] > d);
    const float nd = up ? qd[k - 1] : (mid ? d : qd[k]);
    const float nw = up ? qw[k - 1] : (mid ? w : qw[k]);
    qd[k] = nd; qw[k] = nw;
  }
  if (qd[0] > d) { qw[0] = w; qd[0] = d; }
}

// ---------------- K1: counting sort by axis `dim` (single block) -------------
// sorted[pos] = (x,y,z,orig); cursor[b] = END of bin b.
__global__ __launch_bounds__(1024)
void sort_kernel(const float* __restrict__ p, float4* __restrict__ sorted,
                 int* __restrict__ cursor, int dim, int n) {
  __shared__ int h[NBINS];     // counts, then unused
  __shared__ int cur[NBINS];   // scatter cursors (bin starts)
  __shared__ int ssum[1024];
  const int tid = threadIdx.x;

  h[tid] = 0; h[tid + 1024] = 0;
  __syncthreads();

  for (int i = tid; i < n; i += 1024)
    atomicAdd(&h[bin_of(p[3 * i + dim])], 1);
  __syncthreads();

  const int a = h[2 * tid], b = h[2 * tid + 1];
  ssum[tid] = a + b;
  __syncthreads();
  for (int off = 1; off < 1024; off <<= 1) {
    const int v = (tid >= off) ? ssum[tid - off] : 0;
    __syncthreads();
    ssum[tid] += v;
    __syncthreads();
  }
  const int excl = ssum[tid] - (a + b);
  cur[2 * tid]     = excl;
  cur[2 * tid + 1] = excl + a;
  cursor[2 * tid]     = excl + a;         // end of bin 2t
  cursor[2 * tid + 1] = excl + a + b;     // end of bin 2t+1
  __syncthreads();

  for (int i = tid; i < n; i += 1024) {
    const float x = p[3 * i], y = p[3 * i + 1], z = p[3 * i + 2];
    const float c = (dim == 0) ? x : (dim == 1) ? y : z;
    const int pos = atomicAdd(&cur[bin_of(c)], 1);
    sorted[pos] = make_float4(x, y, z, __int_as_float(i));
  }
}

// ---------------- K2: query (one wave per query, best-axis extent) -----------
__global__ __launch_bounds__(BLOCK)
void query_kernel(const float4* __restrict__ sx, const float4* __restrict__ sy,
                  const float4* __restrict__ sz, const int* __restrict__ cx,
                  const int* __restrict__ cy, const int* __restrict__ cz,
                  const float* __restrict__ W, const float* __restrict__ bias,
                  float* __restrict__ out, int n) {
  const int lane = threadIdx.x & 63;
  const int wv   = threadIdx.x >> 6;
  const int t    = wv * (n >> 2) + blockIdx.x;     // quartile interleave
  const float W0 = W[0], W1 = W[1], W2 = W[2];
  const float bb = bias[0];

  const float4 me = sx[t];                          // enumerate via x-sorted
  const float xi = me.x, yi = me.y, zi = me.z;
  const int orig = __float_as_int(me.w);

  // ---- choose axis with max |coord| (wave-uniform) ----
  const float ax = fabsf(xi), ay = fabsf(yi), az = fabsf(zi);
  const float4* sv; const int* cur; float cq;
  if (ay >= ax && ay >= az)      { sv = sy; cur = cy; cq = yi; }
  else if (az >= ax && az >= ay) { sv = sz; cur = cz; cq = zi; }
  else                           { sv = sx; cur = cx; cq = xi; }

  // ---- bin-estimated rank -> seed window ----
  const int bq = bin_of(cq);
  const int bs = (bq > 0) ? cur[bq - 1] : 0;
  const int be = cur[bq];
  int lo = ((bs + be) >> 1) - SEED / 2;
  lo = lo < 0 ? 0 : lo;
  lo = lo > n - SEED ? n - SEED : lo;
  const float4* base = sv + lo + lane;

  // ---- 1. seed lane-minima ----
  float m = BIG;
#pragma unroll
  for (int s = 0; s < SEED / 64; ++s) {
    const float4 c = base[s * 64];
    const float dx = xi - c.x, dy = yi - c.y, dz = zi - c.z;
    m = fminf(m, fmaf(dx, dx, fmaf(dy, dy, dz * dz)));
  }

  // ---- 2. u = 12th smallest of the 64 lane minima ----
  float u;
  {
    float v = m;
#pragma unroll
    for (int r = 0; r < KK; ++r) {
      const float mm = wave_min(v);
      u = mm;
      v = (v == mm) ? BIG : v;
    }
  }

  // ---- 3. extent from prefix sums: {|c - cq| <= sqrt(u)} ⊆ [lo2, hi2) ----
  const float s = sqrtf(u);
  const int bl = bin_of(cq - s);
  const int bh = bin_of(cq + s);
  const int lo2 = (bl > 0) ? cur[bl - 1] : 0;
  const int hi2 = cur[bh];
  const int steps = (hi2 - lo2 + 63) >> 6;

  // ---- collect-scan: fixed-trip, break-free ----
  float qd[CD], qw[CD];
  int ccnt = 0;
#pragma unroll
  for (int k = 0; k < CD; ++k) { qd[k] = BIG; qw[k] = 0.f; }

  int st = 0;
  for (; st + 2 <= steps; st += 2) {
    const int p0 = lo2 + st * 64 + lane;
    const int p1 = p0 + 64;
    const float4 c0 = sv[p0];
    const float4 c1 = sv[(p1 < hi2) ? p1 : hi2 - 1];
    {
      const float dx = xi - c0.x, dy = yi - c0.y, dz = zi - c0.z;
      const float d2 = fmaf(dx, dx, fmaf(dy, dy, dz * dz));
      if (d2 <= u) {
        const float w = fmaf(W0, fabsf(dx), fmaf(W1, fabsf(dy), W2 * fabsf(dz)));
        ++ccnt; ins4(qd, qw, d2, w);
      }
    }
    if (p1 < hi2) {
      const float dx = xi - c1.x, dy = yi - c1.y, dz = zi - c1.z;
      const float d2 = fmaf(dx, dx, fmaf(dy, dy, dz * dz));
      if (d2 <= u) {
        const float w = fmaf(W0, fabsf(dx), fmaf(W1, fabsf(dy), W2 * fabsf(dz)));
        ++ccnt; ins4(qd, qw, d2, w);
      }
    }
  }
  for (; st < steps; ++st) {
    const int pos = lo2 + st * 64 + lane;
    if (pos < hi2) {
      const float4 c = sv[pos];
      const float dx = xi - c.x, dy = yi - c.y, dz = zi - c.z;
      const float d2 = fmaf(dx, dx, fmaf(dy, dy, dz * dz));
      if (d2 <= u) {
        const float w = fmaf(W0, fabsf(dx), fmaf(W1, fabsf(dy), W2 * fabsf(dz)));
        ++ccnt; ins4(qd, qw, d2, w);
      }
    }
  }

  // ---- 4. extract exact 12 smallest ----
  float acc = 0.f;
  const bool ovf = __ballot(ccnt > CD) != 0ULL;   // wave-uniform
  if (!ovf) {
#pragma unroll
    for (int r = 0; r < KK; ++r) {
      const float mm = wave_min(qd[0]);
      const unsigned long long bal = __ballot(qd[0] == mm);
      if (qd[0] == mm && lane == (int)(__ffsll(bal) - 1)) {
        acc += qw[0];
#pragma unroll
        for (int k = 0; k < CD - 1; ++k) { qd[k] = qd[k + 1]; qw[k] = qw[k + 1]; }
        qd[CD - 1] = BIG;
      }
    }
  } else {
    // rare exact fallback over the same extent: med3 top-12 -> tau -> rescan
    float dd[KK];
#pragma unroll
    for (int k = 0; k < KK; ++k) dd[k] = BIG;
    for (int s0 = 0; s0 < steps; ++s0) {
      const int pos = lo2 + s0 * 64 + lane;
      const float4 c = sv[(pos < hi2) ? pos : hi2 - 1];
      const float dx = xi - c.x, dy = yi - c.y, dz = zi - c.z;
      const float d2 = (pos < hi2) ? fmaf(dx, dx, fmaf(dy, dy, dz * dz)) : BIG;
#pragma unroll
      for (int k = KK - 1; k >= 1; --k)
        dd[k] = __builtin_amdgcn_fmed3f(d2, dd[k - 1], dd[k]);
      dd[0] = fminf(dd[0], d2);
    }
    float tau = 0.f;
#pragma unroll
    for (int r = 0; r < KK; ++r) {
      const float mm = wave_min(dd[0]);
      if (dd[0] == mm) {
#pragma unroll
        for (int k = 0; k < KK - 1; ++k) dd[k] = dd[k + 1];
        dd[KK - 1] = BIG;
      }
      tau = mm;
    }
    for (int s0 = 0; s0 < steps; ++s0) {
      const int pos = lo2 + s0 * 64 + lane;
      if (pos < hi2) {
        const float4 c = sv[pos];
        const float dx = xi - c.x, dy = yi - c.y, dz = zi - c.z;
        const float d2 = fmaf(dx, dx, fmaf(dy, dy, dz * dz));
        const float w  = fmaf(W0, fabsf(dx), fmaf(W1, fabsf(dy), W2 * fabsf(dz)));
        acc += (d2 <= tau) ? w : 0.f;
      }
    }
  }

  // ---- 5. reduce + write ----
#pragma unroll
  for (int o = 1; o < 64; o <<= 1) acc += __shfl_xor(acc, o);
  if (lane == 0) {
    const float xw0 = W0 * xi + W1 * yi + W2 * zi;
    // 1 + 11/sqrt(2)
    out[orig] = bb + (xw0 * 8.778174593052022f + 0.5f * acc) * (1.0f / 12.0f);
  }
}

extern "C" void kernel_launch(void* const* d_in, const int* in_sizes, int n_in,
                              void* d_out, int out_size, void* d_ws, size_t ws_size,
                              hipStream_t stream) {
  const float* p  = (const float*)d_in[0];
  const float* W  = (const float*)d_in[1];
  const float* bb = (const float*)d_in[2];
  float* out = (float*)d_out;

  const int n = in_sizes[0] / 3;   // 16384

  // ws: cursor_x/y/z [2048 ints each] @0 | sorted_x/y/z [16n bytes each]
  int*    cx = (int*)d_ws;
  int*    cy = cx + NBINS;
  int*    cz = cy + NBINS;
  float4* sx = (float4*)((char*)d_ws + 3 * NBINS * 4);
  float4* sy = sx + n;
  float4* sz = sy + n;

  sort_kernel<<<1, 1024, 0, stream>>>(p, sx, cx, 0, n);
  sort_kernel<<<1, 1024, 0, stream>>>(p, sy, cy, 1, n);
  sort_kernel<<<1, 1024, 0, stream>>>(p, sz, cz, 2, n);
  query_kernel<<<n / WPB, BLOCK, 0, stream>>>(sx, sy, sz, cx, cy, cz, W, bb, out, n);
}

// Round 14
// 132.858 us; speedup vs baseline: 3.4650x; 1.2539x over previous
//
#include <hip/hip_runtime.h>
#include <math.h>

// n=16384 Gaussian points in 3D. Exact 12-NN (incl self) per point:
//   out[i] = b + ( (W·p_i)·(1 + 11/sqrt(2)) + 0.5 * sum_{11NN} W·|p_i - p_j| ) / 12
//
// R14: ONE fused sort kernel, grid=3 (blockIdx = axis; three independent
// single-block LDS counting sorts run CONCURRENTLY — R13 serialized them as
// 3 dispatches ≈ 75 µs of the 167 µs total). Query kernel unchanged from R13
// (verified: 68 µs, VALUBusy 48%, occ 36%, prediction matched):
//   one wave per query; pick axis with max |coord| (slab mass minimized ->
//   ~uniform ~30-step extents for all queries); seed 768 around bin-estimated
//   rank -> per-lane min d2 -> u = 12th of 64 lane minima (valid UB of tau)
//   -> extent from prefix sums -> fixed-trip collect into 4-deep paired
//   (d2,w) buffer -> 12-round paired knockout (exact take-12, first-lane
//   tie-break) -> reduce, write. Overflow (rare, wave-uniform) -> exact med3
//   fallback over the same extent. Self contributes w=0.

#define NBINS  2048
#define CMIN_  (-6.0f)
#define INVBW_ ((float)NBINS / 12.0f)
#define BLOCK  256
#define WPB    4
#define SEED   768
#define KK     12
#define CD     4
#define BIG    3.0e38f

__device__ __forceinline__ int bin_of(float x) {
  int b = (int)((x - CMIN_) * INVBW_);
  b = b < 0 ? 0 : b;
  b = b > NBINS - 1 ? NBINS - 1 : b;
  return b;
}

__device__ __forceinline__ float wave_min(float v) {
#pragma unroll
  for (int o = 1; o < 64; o <<= 1) v = fminf(v, __shfl_xor(v, o));
  return v;
}

// sorted ascending 4-deep paired insert (static indexing -> registers)
__device__ __forceinline__ void ins4(float (&qd)[CD], float (&qw)[CD],
                                     float d, float w) {
#pragma unroll
  for (int k = CD - 1; k >= 1; --k) {
    const bool up  = (qd[k - 1] > d);
    const bool mid = (qd[k] > d);
    const float nd = up ? qd[k - 1] : (mid ? d : qd[k]);
    const float nw = up ? qw[k - 1] : (mid ? w : qw[k]);
    qd[k] = nd; qw[k] = nw;
  }
  if (qd[0] > d) { qw[0] = w; qd[0] = d; }
}

// ---------------- K1: fused 3-axis counting sort (grid = 3, one axis/block) --
// sorted[pos] = (x,y,z,orig); cursor[b] = END of bin b.
__global__ __launch_bounds__(1024)
void sort3_kernel(const float* __restrict__ p, float4* __restrict__ s_all,
                  int* __restrict__ c_all, int n) {
  __shared__ int h[NBINS];     // counts
  __shared__ int cur[NBINS];   // scatter cursors (bin starts)
  __shared__ int ssum[1024];
  const int tid = threadIdx.x;
  const int dim = blockIdx.x;                    // 0,1,2
  float4* __restrict__ sorted = s_all + (size_t)dim * n;
  int* __restrict__ cursor    = c_all + (size_t)dim * NBINS;

  h[tid] = 0; h[tid + 1024] = 0;
  __syncthreads();

  for (int i = tid; i < n; i += 1024)
    atomicAdd(&h[bin_of(p[3 * i + dim])], 1);
  __syncthreads();

  const int a = h[2 * tid], b = h[2 * tid + 1];
  ssum[tid] = a + b;
  __syncthreads();
  for (int off = 1; off < 1024; off <<= 1) {
    const int v = (tid >= off) ? ssum[tid - off] : 0;
    __syncthreads();
    ssum[tid] += v;
    __syncthreads();
  }
  const int excl = ssum[tid] - (a + b);
  cur[2 * tid]     = excl;
  cur[2 * tid + 1] = excl + a;
  cursor[2 * tid]     = excl + a;         // end of bin 2t
  cursor[2 * tid + 1] = excl + a + b;     // end of bin 2t+1
  __syncthreads();

  for (int i = tid; i < n; i += 1024) {
    const float x = p[3 * i], y = p[3 * i + 1], z = p[3 * i + 2];
    const float c = (dim == 0) ? x : (dim == 1) ? y : z;
    const int pos = atomicAdd(&cur[bin_of(c)], 1);
    sorted[pos] = make_float4(x, y, z, __int_as_float(i));
  }
}

// ---------------- K2: query (one wave per query, best-axis extent) -----------
__global__ __launch_bounds__(BLOCK)
void query_kernel(const float4* __restrict__ sx, const float4* __restrict__ sy,
                  const float4* __restrict__ sz, const int* __restrict__ cx,
                  const int* __restrict__ cy, const int* __restrict__ cz,
                  const float* __restrict__ W, const float* __restrict__ bias,
                  float* __restrict__ out, int n) {
  const int lane = threadIdx.x & 63;
  const int wv   = threadIdx.x >> 6;
  const int t    = wv * (n >> 2) + blockIdx.x;     // quartile interleave
  const float W0 = W[0], W1 = W[1], W2 = W[2];
  const float bb = bias[0];

  const float4 me = sx[t];                          // enumerate via x-sorted
  const float xi = me.x, yi = me.y, zi = me.z;
  const int orig = __float_as_int(me.w);

  // ---- choose axis with max |coord| (wave-uniform) ----
  const float ax = fabsf(xi), ay = fabsf(yi), az = fabsf(zi);
  const float4* sv; const int* cur; float cq;
  if (ay >= ax && ay >= az)      { sv = sy; cur = cy; cq = yi; }
  else if (az >= ax && az >= ay) { sv = sz; cur = cz; cq = zi; }
  else                           { sv = sx; cur = cx; cq = xi; }

  // ---- bin-estimated rank -> seed window ----
  const int bq = bin_of(cq);
  const int bs = (bq > 0) ? cur[bq - 1] : 0;
  const int be = cur[bq];
  int lo = ((bs + be) >> 1) - SEED / 2;
  lo = lo < 0 ? 0 : lo;
  lo = lo > n - SEED ? n - SEED : lo;
  const float4* base = sv + lo + lane;

  // ---- 1. seed lane-minima ----
  float m = BIG;
#pragma unroll
  for (int s = 0; s < SEED / 64; ++s) {
    const float4 c = base[s * 64];
    const float dx = xi - c.x, dy = yi - c.y, dz = zi - c.z;
    m = fminf(m, fmaf(dx, dx, fmaf(dy, dy, dz * dz)));
  }

  // ---- 2. u = 12th smallest of the 64 lane minima ----
  float u;
  {
    float v = m;
#pragma unroll
    for (int r = 0; r < KK; ++r) {
      const float mm = wave_min(v);
      u = mm;
      v = (v == mm) ? BIG : v;
    }
  }

  // ---- 3. extent from prefix sums: {|c - cq| <= sqrt(u)} ⊆ [lo2, hi2) ----
  const float s = sqrtf(u);
  const int bl = bin_of(cq - s);
  const int bh = bin_of(cq + s);
  const int lo2 = (bl > 0) ? cur[bl - 1] : 0;
  const int hi2 = cur[bh];
  const int steps = (hi2 - lo2 + 63) >> 6;

  // ---- collect-scan: fixed-trip, break-free ----
  float qd[CD], qw[CD];
  int ccnt = 0;
#pragma unroll
  for (int k = 0; k < CD; ++k) { qd[k] = BIG; qw[k] = 0.f; }

  int st = 0;
  for (; st + 2 <= steps; st += 2) {
    const int p0 = lo2 + st * 64 + lane;
    const int p1 = p0 + 64;
    const float4 c0 = sv[p0];
    const float4 c1 = sv[(p1 < hi2) ? p1 : hi2 - 1];
    {
      const float dx = xi - c0.x, dy = yi - c0.y, dz = zi - c0.z;
      const float d2 = fmaf(dx, dx, fmaf(dy, dy, dz * dz));
      if (d2 <= u) {
        const float w = fmaf(W0, fabsf(dx), fmaf(W1, fabsf(dy), W2 * fabsf(dz)));
        ++ccnt; ins4(qd, qw, d2, w);
      }
    }
    if (p1 < hi2) {
      const float dx = xi - c1.x, dy = yi - c1.y, dz = zi - c1.z;
      const float d2 = fmaf(dx, dx, fmaf(dy, dy, dz * dz));
      if (d2 <= u) {
        const float w = fmaf(W0, fabsf(dx), fmaf(W1, fabsf(dy), W2 * fabsf(dz)));
        ++ccnt; ins4(qd, qw, d2, w);
      }
    }
  }
  for (; st < steps; ++st) {
    const int pos = lo2 + st * 64 + lane;
    if (pos < hi2) {
      const float4 c = sv[pos];
      const float dx = xi - c.x, dy = yi - c.y, dz = zi - c.z;
      const float d2 = fmaf(dx, dx, fmaf(dy, dy, dz * dz));
      if (d2 <= u) {
        const float w = fmaf(W0, fabsf(dx), fmaf(W1, fabsf(dy), W2 * fabsf(dz)));
        ++ccnt; ins4(qd, qw, d2, w);
      }
    }
  }

  // ---- 4. extract exact 12 smallest ----
  float acc = 0.f;
  const bool ovf = __ballot(ccnt > CD) != 0ULL;   // wave-uniform
  if (!ovf) {
#pragma unroll
    for (int r = 0; r < KK; ++r) {
      const float mm = wave_min(qd[0]);
      const unsigned long long bal = __ballot(qd[0] == mm);
      if (qd[0] == mm && lane == (int)(__ffsll(bal) - 1)) {
        acc += qw[0];
#pragma unroll
        for (int k = 0; k < CD - 1; ++k) { qd[k] = qd[k + 1]; qw[k] = qw[k + 1]; }
        qd[CD - 1] = BIG;
      }
    }
  } else {
    // rare exact fallback over the same extent: med3 top-12 -> tau -> rescan
    float dd[KK];
#pragma unroll
    for (int k = 0; k < KK; ++k) dd[k] = BIG;
    for (int s0 = 0; s0 < steps; ++s0) {
      const int pos = lo2 + s0 * 64 + lane;
      const float4 c = sv[(pos < hi2) ? pos : hi2 - 1];
      const float dx = xi - c.x, dy = yi - c.y, dz = zi - c.z;
      const float d2 = (pos < hi2) ? fmaf(dx, dx, fmaf(dy, dy, dz * dz)) : BIG;
#pragma unroll
      for (int k = KK - 1; k >= 1; --k)
        dd[k] = __builtin_amdgcn_fmed3f(d2, dd[k - 1], dd[k]);
      dd[0] = fminf(dd[0], d2);
    }
    float tau = 0.f;
#pragma unroll
    for (int r = 0; r < KK; ++r) {
      const float mm = wave_min(dd[0]);
      if (dd[0] == mm) {
#pragma unroll
        for (int k = 0; k < KK - 1; ++k) dd[k] = dd[k + 1];
        dd[KK - 1] = BIG;
      }
      tau = mm;
    }
    for (int s0 = 0; s0 < steps; ++s0) {
      const int pos = lo2 + s0 * 64 + lane;
      if (pos < hi2) {
        const float4 c = sv[pos];
        const float dx = xi - c.x, dy = yi - c.y, dz = zi - c.z;
        const float d2 = fmaf(dx, dx, fmaf(dy, dy, dz * dz));
        const float w  = fmaf(W0, fabsf(dx), fmaf(W1, fabsf(dy), W2 * fabsf(dz)));
        acc += (d2 <= tau) ? w : 0.f;
      }
    }
  }

  // ---- 5. reduce + write ----
#pragma unroll
  for (int o = 1; o < 64; o <<= 1) acc += __shfl_xor(acc, o);
  if (lane == 0) {
    const float xw0 = W0 * xi + W1 * yi + W2 * zi;
    // 1 + 11/sqrt(2)
    out[orig] = bb + (xw0 * 8.778174593052022f + 0.5f * acc) * (1.0f / 12.0f);
  }
}

extern "C" void kernel_launch(void* const* d_in, const int* in_sizes, int n_in,
                              void* d_out, int out_size, void* d_ws, size_t ws_size,
                              hipStream_t stream) {
  const float* p  = (const float*)d_in[0];
  const float* W  = (const float*)d_in[1];
  const float* bb = (const float*)d_in[2];
  float* out = (float*)d_out;

  const int n = in_sizes[0] / 3;   // 16384

  // ws: cursor_x/y/z [2048 ints each] @0 | sorted_x/y/z [16n bytes each]
  int*    c_all = (int*)d_ws;
  float4* s_all = (float4*)((char*)d_ws + 3 * NBINS * 4);
  int*    cx = c_all;
  int*    cy = cx + NBINS;
  int*    cz = cy + NBINS;
  float4* sx = s_all;
  float4* sy = sx + n;
  float4* sz = sy + n;

  sort3_kernel<<<3, 1024, 0, stream>>>(p, s_all, c_all, n);
  query_kernel<<<n / WPB, BLOCK, 0, stream>>>(sx, sy, sz, cx, cy, cz, W, bb, out, n);
}